// Round 4
// baseline (980.589 us; speedup 1.0000x reference)
//
#include <hip/hip_runtime.h>
#include <stdint.h>

#define BATCH 8
#define NPTS  65536
#define CFEAT 256
#define K1    259     // 3 + 256
#define K1PAD 288     // 9 * 32
#define CH    128
#define NS    1024
#define EPSF  1e-5f
#define INVN  (1.0f / (BATCH * NS))
#define WS_STRIDE 132
#define XS_STRIDE 36

// Order-preserving float<->uint mapping for atomicMax/atomicMin on floats.
__device__ __forceinline__ unsigned fenc(float f) {
  unsigned u = __float_as_uint(f);
  return (u & 0x80000000u) ? ~u : (u | 0x80000000u);
}
__device__ __forceinline__ float fdec(unsigned k) {
  unsigned u = (k & 0x80000000u) ? (k & 0x7fffffffu) : ~k;
  return __uint_as_float(u);
}

// Agent-scope atomic load/store: cross-XCD-safe communication through LLC.
__device__ __forceinline__ float aload_f(const float* p) {
  return __hip_atomic_load(p, __ATOMIC_RELAXED, __HIP_MEMORY_SCOPE_AGENT);
}
__device__ __forceinline__ void astore_f(float* p, float v) {
  __hip_atomic_store(p, v, __ATOMIC_RELAXED, __HIP_MEMORY_SCOPE_AGENT);
}
__device__ __forceinline__ int aload_i(const int* p) {
  return __hip_atomic_load(p, __ATOMIC_RELAXED, __HIP_MEMORY_SCOPE_AGENT);
}
__device__ __forceinline__ void astore_i(int* p, int v) {
  __hip_atomic_store(p, v, __ATOMIC_RELAXED, __HIP_MEMORY_SCOPE_AGENT);
}
__device__ __forceinline__ unsigned aload_u(const unsigned* p) {
  return __hip_atomic_load(p, __ATOMIC_RELAXED, __HIP_MEMORY_SCOPE_AGENT);
}
__device__ __forceinline__ void astore_u(unsigned* p, unsigned v) {
  __hip_atomic_store(p, v, __ATOMIC_RELAXED, __HIP_MEMORY_SCOPE_AGENT);
}

// Monotone grid barrier. Cooperative launch guarantees all 256 blocks are
// co-resident (1 block/CU via 110 KB LDS, 256 CUs).
__device__ __forceinline__ void gsync(unsigned* bar, unsigned target) {
  __syncthreads();
  if (threadIdx.x == 0) {
    __hip_atomic_fetch_add(bar, 1u, __ATOMIC_ACQ_REL, __HIP_MEMORY_SCOPE_AGENT);
    while (__hip_atomic_load(bar, __ATOMIC_ACQUIRE, __HIP_MEMORY_SCOPE_AGENT) < target)
      __builtin_amdgcn_s_sleep(2);
  }
  __syncthreads();
}

#define FMA16(wv, xv) do { \
  acc[0][0] += wv.x*xv.x; acc[0][1] += wv.x*xv.y; acc[0][2] += wv.x*xv.z; acc[0][3] += wv.x*xv.w; \
  acc[1][0] += wv.y*xv.x; acc[1][1] += wv.y*xv.y; acc[1][2] += wv.y*xv.z; acc[1][3] += wv.y*xv.w; \
  acc[2][0] += wv.z*xv.x; acc[2][1] += wv.z*xv.y; acc[2][2] += wv.z*xv.z; acc[2][3] += wv.z*xv.w; \
  acc[3][0] += wv.w*xv.x; acc[3][1] += wv.w*xv.y; acc[3][2] += wv.w*xv.z; acc[3][3] += wv.w*xv.w; \
} while (0)

struct KParams {
  const float *xyz, *feat;
  const float *w1, *b1, *ga1, *be1;
  const float *w2, *b2, *ga2, *be2;
  const float *w3, *b3, *ga3, *be3;
  const float *hw1, *hb1, *hg1, *hbe1;
  const float *hw2, *hb2, *hg2, *hbe2;
  const float *hw3, *hb3;
  int* inds;
  float* center;
  float *sums1, *sums2, *sums3;
  unsigned *maxk, *mink, *bar;
  float* out;
};

// Y tile (128x32, +bias) -> LDS rows 0..127 of Xs; BN partial stats -> atomics.
__device__ __forceinline__ void y_to_lds_and_stats(float* __restrict__ XsB,
                                                   float* __restrict__ sums,
                                                   const float* __restrict__ bias,
                                                   float (&acc)[4][4], int tx, int ty) {
#pragma unroll
  for (int r = 0; r < 4; ++r) {
    int o = ty * 4 + r;
    float bs = bias[o];
    float4 v = make_float4(acc[r][0] + bs, acc[r][1] + bs,
                           acc[r][2] + bs, acc[r][3] + bs);
    *(float4*)&XsB[o * XS_STRIDE + tx * 4] = v;
    float s = v.x + v.y + v.z + v.w;
    float q = v.x * v.x + v.y * v.y + v.z * v.z + v.w * v.w;
    s += __shfl_xor(s, 1, 64); q += __shfl_xor(q, 1, 64);
    s += __shfl_xor(s, 2, 64); q += __shfl_xor(q, 2, 64);
    s += __shfl_xor(s, 4, 64); q += __shfl_xor(q, 4, 64);
    if (tx == 0) { atomicAdd(&sums[o], s); atomicAdd(&sums[CH + o], q); }
  }
}

// One K=128 layer: stage full W (128x128) into LDS, BN+ReLU the X tile in
// place, then the 128-step FMA loop. Ends with a sync.
__device__ __forceinline__ void mlp_layer(float* __restrict__ XsB, float* __restrict__ WsB,
                                          const float* __restrict__ scl_s,
                                          const float* __restrict__ shf_s,
                                          const float* __restrict__ W,
                                          int tid, int tx, int ty, float (&acc)[4][4]) {
#pragma unroll 16
  for (int i = 0; i < 64; ++i) {
    int e = tid + 256 * i;
    int o = e >> 7, kk = e & 127;
    WsB[kk * WS_STRIDE + o] = W[o * CH + kk];
  }
  __syncthreads();
#pragma unroll 4
  for (int i = 0; i < 16; ++i) {
    int e = tid + 256 * i;
    int k = e >> 5, j = e & 31;
    float v = XsB[k * XS_STRIDE + j];
    XsB[k * XS_STRIDE + j] = fmaxf(scl_s[k] * v + shf_s[k], 0.f);
  }
  __syncthreads();
#pragma unroll 8
  for (int kk = 0; kk < CH; ++kk) {
    float4 xv = *(const float4*)&XsB[kk * XS_STRIDE + tx * 4];
    float4 wv = *(const float4*)&WsB[kk * WS_STRIDE + ty * 4];
    FMA16(wv, xv);
  }
  __syncthreads();
}

__global__ __launch_bounds__(256, 1) void k_fused(KParams P) {
  __shared__ float WsBig[CH * WS_STRIDE];     // 67.6 KB (layer-1 uses rows 0..31)
  __shared__ float Xs[K1PAD * XS_STRIDE];     // 41.5 KB: X1 -> Y1/X2 -> Y2/X3 -> head A/Bm
  __shared__ float scl[CH], shf[CH];
  __shared__ int   ids[32];
  __shared__ float cenl[3];
  __shared__ int   wsum[2][4];

  int blk = blockIdx.x;
  int tid = threadIdx.x;

  // ------------------- phase 0: select (blocks 0..7) + init (block 8) ------
  if (blk < BATCH) {
    const float* xb = P.xyz + (size_t)blk * NPTS * 3;
    if (tid < 3) astore_f(&P.center[blk * 3 + tid], xb[tid]);
    float cx = xb[0], cy = xb[1], cz = xb[2];
    int* ib = P.inds + blk * NS;
    int lane = tid & 63, wid = tid >> 6;
    int total = 0, par = 0;
    for (int base = 0; base < NPTS && total < NS; base += 1024) {
      int i0 = base + tid * 4;
      const float* pp = &xb[(size_t)i0 * 3];
      float4 q0 = *(const float4*)pp;
      float4 q1 = *(const float4*)(pp + 4);
      float4 q2 = *(const float4*)(pp + 8);
      float dx, dy, dz;
      dx = q0.x - cx; dy = q0.y - cy; dz = q0.z - cz; bool p0 = dx*dx + dy*dy + dz*dz < 1.f;
      dx = q0.w - cx; dy = q1.x - cy; dz = q1.y - cz; bool p1 = dx*dx + dy*dy + dz*dz < 1.f;
      dx = q1.z - cx; dy = q1.w - cy; dz = q2.x - cz; bool p2 = dx*dx + dy*dy + dz*dz < 1.f;
      dx = q2.y - cx; dy = q2.z - cy; dz = q2.w - cz; bool p3 = dx*dx + dy*dy + dz*dz < 1.f;
      int cnt = (int)p0 + (int)p1 + (int)p2 + (int)p3;
      int scan = cnt;
#pragma unroll
      for (int o = 1; o < 64; o <<= 1) {
        int t = __shfl_up(scan, o, 64);
        if (lane >= o) scan += t;
      }
      if (lane == 63) wsum[par][wid] = scan;
      __syncthreads();
      int w0 = wsum[par][0], w1_ = wsum[par][1], w2_ = wsum[par][2], w3_ = wsum[par][3];
      int woff = (wid > 0 ? w0 : 0) + (wid > 1 ? w1_ : 0) + (wid > 2 ? w2_ : 0);
      int pos = total + woff + (scan - cnt);
      if (p0 && pos < NS) astore_i(&ib[pos], i0);     pos += p0;
      if (p1 && pos < NS) astore_i(&ib[pos], i0 + 1); pos += p1;
      if (p2 && pos < NS) astore_i(&ib[pos], i0 + 2); pos += p2;
      if (p3 && pos < NS) astore_i(&ib[pos], i0 + 3); pos += p3;
      total += w0 + w1_ + w2_ + w3_;
      par ^= 1;
    }
    for (int j = total + tid; j < NS; j += 256) astore_i(&ib[j], 0);
  } else if (blk == 8) {
    if (tid < 2 * CH) {
      astore_f(&P.sums1[tid], 0.f);
      astore_f(&P.sums2[tid], 0.f);
      astore_f(&P.sums3[tid], 0.f);
    }
#pragma unroll
    for (int i = 0; i < 4; ++i) {
      int e = tid + 256 * i;                 // BATCH*CH = 1024
      astore_u(&P.maxk[e], 0u);
      astore_u(&P.mink[e], 0xFFFFFFFFu);
    }
  }
  gsync(P.bar, 256);

  // ------------------- phase 1: gather + GEMM1 (K=259) ---------------------
  int b = blk >> 5;
  int n0 = (blk & 31) * 32;
  int tx = tid & 7, ty = tid >> 3;

  if (tid < 32) ids[tid] = aload_i(&P.inds[b * NS + n0 + tid]);
  if (tid < 3)  cenl[tid] = aload_f(&P.center[b * 3 + tid]);
  __syncthreads();

  const float* featb = P.feat + (size_t)b * CFEAT * NPTS;
  const float* xyzb  = P.xyz + (size_t)b * NPTS * 3;
  if (tid < 96) {
    int k = tid >> 5, j = tid & 31;
    Xs[k * XS_STRIDE + j] = xyzb[(size_t)ids[j] * 3 + k] - cenl[k];
  }
  for (int e = tid; e < 29 * 32; e += 256)      // zero rows 259..287
    Xs[(K1 + (e >> 5)) * XS_STRIDE + (e & 31)] = 0.f;
  {
    // 32 scattered loads per thread, register-staged for max MLP.
    int j = tid & 31, kbase = tid >> 5;
    const float* fp = featb + ids[j];
    float g[32];
#pragma unroll
    for (int i = 0; i < 32; ++i)
      g[i] = fp[(size_t)(kbase + 8 * i) * NPTS];
#pragma unroll
    for (int i = 0; i < 32; ++i)
      Xs[(3 + kbase + 8 * i) * XS_STRIDE + j] = g[i];
  }
  __syncthreads();

  float acc[4][4];
#pragma unroll
  for (int r = 0; r < 4; ++r)
#pragma unroll
    for (int j = 0; j < 4; ++j) acc[r][j] = 0.f;

  for (int k0 = 0; k0 < K1PAD; k0 += 32) {
#pragma unroll
    for (int i = 0; i < 16; ++i) {
      int e = tid + 256 * i;
      int o = e >> 5, kk = e & 31;
      int k = k0 + kk;
      WsBig[kk * WS_STRIDE + o] = (k < K1) ? P.w1[o * K1 + k] : 0.f;
    }
    __syncthreads();
#pragma unroll
    for (int kk = 0; kk < 32; ++kk) {
      float4 xv = *(const float4*)&Xs[(k0 + kk) * XS_STRIDE + tx * 4];
      float4 wv = *(const float4*)&WsBig[kk * WS_STRIDE + ty * 4];
      FMA16(wv, xv);
    }
    __syncthreads();
  }
  y_to_lds_and_stats(Xs, P.sums1, P.b1, acc, tx, ty);
  gsync(P.bar, 512);

  // ------------------- phase 2: BN1+ReLU + GEMM2 ---------------------------
  if (tid < CH) {
    float s = aload_f(&P.sums1[tid]), q = aload_f(&P.sums1[CH + tid]);
    float mean = s * INVN;
    float var = fmaxf(q * INVN - mean * mean, 0.f);
    float sc = P.ga1[tid] * rsqrtf(var + EPSF);
    scl[tid] = sc; shf[tid] = P.be1[tid] - mean * sc;
  }
#pragma unroll
  for (int r = 0; r < 4; ++r)
#pragma unroll
    for (int j = 0; j < 4; ++j) acc[r][j] = 0.f;
  mlp_layer(Xs, WsBig, scl, shf, P.w2, tid, tx, ty, acc);
  y_to_lds_and_stats(Xs, P.sums2, P.b2, acc, tx, ty);
  gsync(P.bar, 768);

  // ------------------- phase 3: BN2+ReLU + GEMM3 + extrema -----------------
  if (tid < CH) {
    float s = aload_f(&P.sums2[tid]), q = aload_f(&P.sums2[CH + tid]);
    float mean = s * INVN;
    float var = fmaxf(q * INVN - mean * mean, 0.f);
    float sc = P.ga2[tid] * rsqrtf(var + EPSF);
    scl[tid] = sc; shf[tid] = P.be2[tid] - mean * sc;
  }
#pragma unroll
  for (int r = 0; r < 4; ++r)
#pragma unroll
    for (int j = 0; j < 4; ++j) acc[r][j] = 0.f;
  mlp_layer(Xs, WsBig, scl, shf, P.w3, tid, tx, ty, acc);

#pragma unroll
  for (int r = 0; r < 4; ++r) {
    int o = ty * 4 + r;
    float bs = P.b3[o];
    float4 v = make_float4(acc[r][0] + bs, acc[r][1] + bs,
                           acc[r][2] + bs, acc[r][3] + bs);
    float s = v.x + v.y + v.z + v.w;
    float q = v.x * v.x + v.y * v.y + v.z * v.z + v.w * v.w;
    float mx = fmaxf(fmaxf(v.x, v.y), fmaxf(v.z, v.w));
    float mn = fminf(fminf(v.x, v.y), fminf(v.z, v.w));
    s += __shfl_xor(s, 1, 64); q += __shfl_xor(q, 1, 64);
    mx = fmaxf(mx, __shfl_xor(mx, 1, 64)); mn = fminf(mn, __shfl_xor(mn, 1, 64));
    s += __shfl_xor(s, 2, 64); q += __shfl_xor(q, 2, 64);
    mx = fmaxf(mx, __shfl_xor(mx, 2, 64)); mn = fminf(mn, __shfl_xor(mn, 2, 64));
    s += __shfl_xor(s, 4, 64); q += __shfl_xor(q, 4, 64);
    mx = fmaxf(mx, __shfl_xor(mx, 4, 64)); mn = fminf(mn, __shfl_xor(mn, 4, 64));
    if (tx == 0) {
      atomicAdd(&P.sums3[o], s);
      atomicAdd(&P.sums3[CH + o], q);
      atomicMax(&P.maxk[b * CH + o], fenc(mx));
      atomicMin(&P.mink[b * CH + o], fenc(mn));
    }
  }
  gsync(P.bar, 1024);

  // ------------------- phase 4: head (block 0) -----------------------------
  if (blk == 0) {
    float* A  = Xs;            // 1024 floats
    float* Bm = Xs + 1024;     // 1024 floats
    int c = tid;
    if (c < CH) {
      float s = aload_f(&P.sums3[c]), q = aload_f(&P.sums3[CH + c]);
      float mean = s * INVN;
      float var = fmaxf(q * INVN - mean * mean, 0.f);
      float sc = P.ga3[c] * rsqrtf(var + EPSF);
      float sh = P.be3[c] - mean * sc;
#pragma unroll
      for (int bb = 0; bb < BATCH; ++bb) {
        float ymax = fdec(aload_u(&P.maxk[bb * CH + c]));
        float ymin = fdec(aload_u(&P.mink[bb * CH + c]));
        float ye = (sc >= 0.f) ? ymax : ymin;
        A[bb * CH + c] = fmaxf(sc * ye + sh, 0.f);
      }
    }
    __syncthreads();
    if (c < CH) {
      float v[BATCH];
      float bs = P.hb1[c];
#pragma unroll
      for (int bb = 0; bb < BATCH; ++bb) v[bb] = bs;
      const float4* w4 = (const float4*)P.hw1 + c * 32;
      for (int k4 = 0; k4 < 32; ++k4) {
        float4 w = w4[k4];
#pragma unroll
        for (int bb = 0; bb < BATCH; ++bb) {
          const float* Ar = &A[bb * CH + k4 * 4];
          v[bb] += Ar[0] * w.x + Ar[1] * w.y + Ar[2] * w.z + Ar[3] * w.w;
        }
      }
      float m = 0.f;
#pragma unroll
      for (int bb = 0; bb < BATCH; ++bb) m += v[bb];
      m *= (1.f / BATCH);
      float var = 0.f;
#pragma unroll
      for (int bb = 0; bb < BATCH; ++bb) { float d = v[bb] - m; var += d * d; }
      var *= (1.f / BATCH);
      float r = rsqrtf(var + EPSF);
      float ga = P.hg1[c], be = P.hbe1[c];
#pragma unroll
      for (int bb = 0; bb < BATCH; ++bb)
        Bm[bb * CH + c] = fmaxf(ga * (v[bb] - m) * r + be, 0.f);
    }
    __syncthreads();
    if (c < CH) {
      float v[BATCH];
      float bs = P.hb2[c];
#pragma unroll
      for (int bb = 0; bb < BATCH; ++bb) v[bb] = bs;
      const float4* w4 = (const float4*)P.hw2 + c * 32;
      for (int k4 = 0; k4 < 32; ++k4) {
        float4 w = w4[k4];
#pragma unroll
        for (int bb = 0; bb < BATCH; ++bb) {
          const float* Br = &Bm[bb * CH + k4 * 4];
          v[bb] += Br[0] * w.x + Br[1] * w.y + Br[2] * w.z + Br[3] * w.w;
        }
      }
      float m = 0.f;
#pragma unroll
      for (int bb = 0; bb < BATCH; ++bb) m += v[bb];
      m *= (1.f / BATCH);
      float var = 0.f;
#pragma unroll
      for (int bb = 0; bb < BATCH; ++bb) { float d = v[bb] - m; var += d * d; }
      var *= (1.f / BATCH);
      float r = rsqrtf(var + EPSF);
      float ga = P.hg2[c], be = P.hbe2[c];
#pragma unroll
      for (int bb = 0; bb < BATCH; ++bb)
        A[bb * CH + c] = fmaxf(ga * (v[bb] - m) * r + be, 0.f);
    }
    __syncthreads();
    if (c < 96) {
      int bb = c / 12, j = c % 12;
      float o = P.hb3[j];
      const float4* w4 = (const float4*)P.hw3 + j * 32;
      for (int k4 = 0; k4 < 32; ++k4) {
        float4 w = w4[k4];
        const float* Ar = &A[bb * CH + k4 * 4];
        o += Ar[0] * w.x + Ar[1] * w.y + Ar[2] * w.z + Ar[3] * w.w;
      }
      if (j < 3)      P.out[bb * 3 + j] = aload_f(&P.center[bb * 3 + j]) + o;
      else if (j < 6) P.out[24 + bb * 3 + (j - 3)] = o;
      else            P.out[48 + bb * 6 + (j - 6)] = o;
    }
  }
}

// ---------------------------------------------------------------------------
extern "C" void kernel_launch(void* const* d_in, const int* in_sizes, int n_in,
                              void* d_out, int out_size, void* d_ws, size_t ws_size,
                              hipStream_t stream) {
  char* ws = (char*)d_ws;
  size_t off = 0;
  auto alloc = [&](size_t bytes) -> void* {
    void* p = ws + off;
    off = (off + bytes + 255) & ~(size_t)255;
    return p;
  };
  float*    sums1  = (float*)alloc(2 * CH * 4);
  float*    sums2  = (float*)alloc(2 * CH * 4);
  float*    sums3  = (float*)alloc(2 * CH * 4);
  unsigned* maxk   = (unsigned*)alloc((size_t)BATCH * CH * 4);
  unsigned* mink   = (unsigned*)alloc((size_t)BATCH * CH * 4);
  int*      inds   = (int*)alloc((size_t)BATCH * NS * 4);
  float*    center = (float*)alloc(BATCH * 3 * 4);
  unsigned* bar    = (unsigned*)alloc(256);

  KParams P;
  P.xyz  = (const float*)d_in[0];
  P.feat = (const float*)d_in[1];
  P.w1   = (const float*)d_in[2];
  P.b1   = (const float*)d_in[3];
  P.ga1  = (const float*)d_in[4];
  P.be1  = (const float*)d_in[5];
  P.w2   = (const float*)d_in[6];
  P.b2   = (const float*)d_in[7];
  P.ga2  = (const float*)d_in[8];
  P.be2  = (const float*)d_in[9];
  P.w3   = (const float*)d_in[10];
  P.b3   = (const float*)d_in[11];
  P.ga3  = (const float*)d_in[12];
  P.be3  = (const float*)d_in[13];
  P.hw1  = (const float*)d_in[14];
  P.hb1  = (const float*)d_in[15];
  P.hg1  = (const float*)d_in[16];
  P.hbe1 = (const float*)d_in[17];
  P.hw2  = (const float*)d_in[18];
  P.hb2  = (const float*)d_in[19];
  P.hg2  = (const float*)d_in[20];
  P.hbe2 = (const float*)d_in[21];
  P.hw3  = (const float*)d_in[22];
  P.hb3  = (const float*)d_in[23];
  P.inds = inds; P.center = center;
  P.sums1 = sums1; P.sums2 = sums2; P.sums3 = sums3;
  P.maxk = maxk; P.mink = mink; P.bar = bar;
  P.out = (float*)d_out;

  hipMemsetAsync(bar, 0, 4, stream);

  void* args[] = { &P };
  hipLaunchCooperativeKernel(reinterpret_cast<const void*>(&k_fused),
                             dim3(256), dim3(256), args, 0, stream);
}